// Round 6
// baseline (216.161 us; speedup 1.0000x reference)
//
#include <hip/hip_runtime.h>
#include <math.h>

typedef _Float16 f16;
typedef _Float16 f16x2 __attribute__((ext_vector_type(2)));
typedef _Float16 f16x4 __attribute__((ext_vector_type(4)));
typedef _Float16 f16x8 __attribute__((ext_vector_type(8)));
typedef __fp16 h16x2 __attribute__((ext_vector_type(2)));
typedef float f32x4 __attribute__((ext_vector_type(4)));

#define N_TOK 2048
#define C_DIM 1024
#define E_NUM 8
#define F_DIM 2048
#define BM 256

// ws layout (bytes)
#define WS_COUNTS    0
#define WS_OFFSETS   64
#define WS_CURSOR    192
#define WS_TOPI      256
#define WS_TOPW      (WS_TOPI + 16384)
#define WS_ROWS      (WS_TOPW + 16384)
#define WS_SLOT      (WS_ROWS + 16384)
#define WS_X16       (1u << 20)    // 4 MB   (2048x1024 f16)
#define WS_H         (6u << 20)    // 16.8 MB (4096x2048 f16)
#define WS_Y0        (23u << 20)   // 8.4 MB (4096x1024 f16)
#define WS_Y1        (32u << 20)   // 8.4 MB

__device__ __forceinline__ void glds16(const void* g, void* l) {
  __builtin_amdgcn_global_load_lds((const __attribute__((address_space(1))) void*)g,
                                   (__attribute__((address_space(3))) void*)l, 16, 0, 0);
}

__device__ __forceinline__ f16x2 pkrtz(float a, float b) {
  union { h16x2 h; f16x2 f; } u;
  u.h = __builtin_amdgcn_cvt_pkrtz(a, b);
  return u.f;
}

// ---------------- x fp32 -> fp16 ----------------
__global__ void cvtx_kernel(const float* __restrict__ x, f16* __restrict__ x16) {
  int i = (blockIdx.x * 256 + threadIdx.x) * 8;
  f32x4 a = *(const f32x4*)(x + i);
  f32x4 b = *(const f32x4*)(x + i + 4);
  union { f16x8 v; f16x2 h[4]; } u;
  u.h[0] = pkrtz(a[0], a[1]);
  u.h[1] = pkrtz(a[2], a[3]);
  u.h[2] = pkrtz(b[0], b[1]);
  u.h[3] = pkrtz(b[2], b[3]);
  *(f16x8*)(x16 + i) = u.v;
}

// ---------------- router ----------------
__global__ void router_kernel(const float* __restrict__ x, const float* __restrict__ Wr,
                              int* counts, int* topi, float* topw) {
  int tok = blockIdx.x * 4 + (threadIdx.x >> 6);
  int lane = threadIdx.x & 63;
  const float* xr = x + (size_t)tok * C_DIM;
  float xv[16];
#pragma unroll
  for (int i = 0; i < 16; ++i) xv[i] = xr[i * 64 + lane];
  float logit[E_NUM];
#pragma unroll
  for (int e = 0; e < E_NUM; ++e) {
    const float* wr = Wr + (size_t)e * C_DIM;
    float acc = 0.f;
#pragma unroll
    for (int i = 0; i < 16; ++i) acc += xv[i] * wr[i * 64 + lane];
#pragma unroll
    for (int s = 1; s < 64; s <<= 1) acc += __shfl_xor(acc, s, 64);
    logit[e] = acc;
  }
  if (lane == 0) {
    float m = logit[0];
#pragma unroll
    for (int e = 1; e < E_NUM; ++e) m = fmaxf(m, logit[e]);
    float p[E_NUM];
#pragma unroll
    for (int e = 0; e < E_NUM; ++e) p[e] = expf(logit[e] - m);
    float p0 = -1.f, p1 = -1.f;
    int i0 = 0, i1 = 0;
#pragma unroll
    for (int e = 0; e < E_NUM; ++e) {
      float v = p[e];
      if (v > p0) { p1 = p0; i1 = i0; p0 = v; i0 = e; }
      else if (v > p1) { p1 = v; i1 = e; }
    }
    float inv = 1.f / (p0 + p1);
    topi[2 * tok] = i0; topi[2 * tok + 1] = i1;
    topw[2 * tok] = p0 * inv; topw[2 * tok + 1] = p1 * inv;
    atomicAdd(&counts[i0], 1);
    atomicAdd(&counts[i1], 1);
  }
}

// ---------------- scan ----------------
__global__ void scan_kernel(const int* counts, int* offsets, int* cursor) {
  if (threadIdx.x == 0) {
    int o = 0;
    for (int e = 0; e < E_NUM; ++e) {
      offsets[e] = o; cursor[e] = o;
      o += counts[e];
    }
    offsets[E_NUM] = o;
  }
}

// ---------------- scatter ----------------
__global__ void scatter_kernel(const int* __restrict__ topi, int* cursor,
                               int* rows_perm, int* slot_of) {
  int n = blockIdx.x * blockDim.x + threadIdx.x;
  if (n >= N_TOK) return;
#pragma unroll
  for (int k = 0; k < 2; ++k) {
    int e = topi[2 * n + k];
    int pos = atomicAdd(&cursor[e], 1);
    rows_perm[pos] = n;
    slot_of[2 * n + k] = pos;
  }
}

// ================= up-proj: h = silu(x@w1)*(x@w3) =================
// 256x128 tile, BK=32, 8 waves. Raw-barrier pipeline, depth-2 prefetch:
// B regs double-banked, A triple-buffered LDS. Expert-locked XCD mapping.
#define UP_STEP(R1, R3)                                                          \
  do {                                                                           \
    { union { f16x8 v; f16x2 h[4]; } u;                                          \
      u.h[0] = pkrtz(R1[0], R1[1]); u.h[1] = pkrtz(R1[2], R1[3]);                \
      u.h[2] = pkrtz(R1[4], R1[5]); u.h[3] = pkrtz(R1[6], R1[7]);                \
      *(f16x8*)&B1_lds[cur][bso] = u.v;                                          \
      u.h[0] = pkrtz(R3[0], R3[1]); u.h[1] = pkrtz(R3[2], R3[3]);                \
      u.h[2] = pkrtz(R3[4], R3[5]); u.h[3] = pkrtz(R3[6], R3[7]);                \
      *(f16x8*)&B3_lds[cur][bso] = u.v; }                                        \
    asm volatile("s_waitcnt lgkmcnt(0)" ::: "memory");                           \
    __builtin_amdgcn_s_barrier();                                                \
    { int kn = ((ti + 2) & 31) * 32;                                             \
      _Pragma("unroll") for (int j = 0; j < 8; ++j) {                            \
        R1[j] = w1p[(size_t)(kn + j) * F_DIM];                                   \
        R3[j] = w3p[(size_t)(kn + j) * F_DIM]; }                                 \
      glds16(asrc[0] + kn, a_wr + wid * 512);                                    \
      glds16(asrc[1] + kn, a_wr + (8 + wid) * 512); }                            \
    asm volatile("s_waitcnt vmcnt(36)" ::: "memory");                            \
    { f16x8 a[4], b[4];                                                          \
      _Pragma("unroll") for (int m = 0; m < 4; ++m) {                            \
        int row = wr + m * 16 + fr;                                              \
        a[m] = *(const f16x8*)&a_rd0[row * 32 + (fq ^ ((row >> 1) & 3)) * 8]; }  \
      _Pragma("unroll") for (int n = 0; n < 4; ++n) {                            \
        int col = wc + n * 16 + fr;                                              \
        b[n] = *(const f16x8*)&B1_lds[cur][col * 32 + (fq ^ ((col >> 1) & 3)) * 8]; } \
      _Pragma("unroll") for (int m = 0; m < 4; ++m)                              \
        _Pragma("unroll") for (int n = 0; n < 4; ++n)                            \
          acc1[m][n] = __builtin_amdgcn_mfma_f32_16x16x32_f16(a[m], b[n], acc1[m][n], 0, 0, 0); \
      _Pragma("unroll") for (int n = 0; n < 4; ++n) {                            \
        int col = wc + n * 16 + fr;                                              \
        b[n] = *(const f16x8*)&B3_lds[cur][col * 32 + (fq ^ ((col >> 1) & 3)) * 8]; } \
      _Pragma("unroll") for (int m = 0; m < 4; ++m)                              \
        _Pragma("unroll") for (int n = 0; n < 4; ++n)                            \
          acc3[m][n] = __builtin_amdgcn_mfma_f32_16x16x32_f16(a[m], b[n], acc3[m][n], 0, 0, 0); } \
    { f16* _t = a_rd0; a_rd0 = a_rd1; a_rd1 = a_wr; a_wr = _t; }                 \
    ++ti; cur ^= 1;                                                              \
  } while (0)

__launch_bounds__(512, 2)
__global__ void upproj_kernel(const f16* __restrict__ x16,
                              const float* __restrict__ w1,
                              const float* __restrict__ w3,
                              const int* __restrict__ counts,
                              const int* __restrict__ offsets,
                              const int* __restrict__ rows_perm,
                              f16* __restrict__ h_buf) {
  __shared__ f16 A_lds[3][BM * 32];
  __shared__ f16 B1_lds[2][128 * 32];
  __shared__ f16 B3_lds[2][128 * 32];

  int bid = blockIdx.x;
  int e = bid & 7;            // expert-locked XCD
  int slot = bid >> 3;        // 0..127
  int tile = slot >> 4;       // 0..7
  int fidx = slot & 15;
  int cnt = counts[e];
  if (tile * BM >= cnt) return;
  int row0 = tile * BM;
  int off = offsets[e];
  int f0 = fidx * 128;
  int t = threadIdx.x, wid = t >> 6, lane = t & 63;

  const f16* asrc[2];
#pragma unroll
  for (int p = 0; p < 2; ++p) {
    int c = (p * 8 + wid) * 64 + lane;
    int row = c >> 2, cc = c & 3;
    int lr = row0 + row; if (lr > cnt - 1) lr = cnt - 1;
    int g = rows_perm[off + lr];
    asrc[p] = x16 + (size_t)g * C_DIM + 8 * (cc ^ ((row >> 1) & 3));
  }

  int bcol = t & 127, kg = t >> 7;
  int bso = bcol * 32 + (kg ^ ((bcol >> 1) & 3)) * 8;
  const size_t eb = (size_t)e * C_DIM * F_DIM;
  const float* w1p = w1 + eb + (size_t)(kg * 8) * F_DIM + f0 + bcol;
  const float* w3p = w3 + eb + (size_t)(kg * 8) * F_DIM + f0 + bcol;

  f32x4 acc1[4][4] = {};
  f32x4 acc3[4][4] = {};
  int wr = (wid >> 1) * 64, wc = (wid & 1) * 64;
  int fr = lane & 15, fq = lane >> 4;

  f16* a_rd0 = &A_lds[0][0];
  f16* a_rd1 = &A_lds[1][0];
  f16* a_wr  = &A_lds[2][0];

  // prologue: issue t=0 and t=1
  float rA1[8], rA3[8], rB1[8], rB3[8];
#pragma unroll
  for (int j = 0; j < 8; ++j) { rA1[j] = w1p[(size_t)j * F_DIM]; rA3[j] = w3p[(size_t)j * F_DIM]; }
  glds16(asrc[0], a_rd0 + wid * 512);
  glds16(asrc[1], a_rd0 + (8 + wid) * 512);
#pragma unroll
  for (int j = 0; j < 8; ++j) { rB1[j] = w1p[(size_t)(32 + j) * F_DIM]; rB3[j] = w3p[(size_t)(32 + j) * F_DIM]; }
  glds16(asrc[0] + 32, a_rd1 + wid * 512);
  glds16(asrc[1] + 32, a_rd1 + (8 + wid) * 512);

  int ti = 0, cur = 0;
  for (int tp = 0; tp < 16; ++tp) {
    UP_STEP(rA1, rA3);
    UP_STEP(rB1, rB3);
  }

#pragma unroll
  for (int m = 0; m < 4; ++m)
#pragma unroll
    for (int n = 0; n < 4; ++n)
#pragma unroll
      for (int i = 0; i < 4; ++i) {
        int lr = row0 + wr + m * 16 + fq * 4 + i;
        if (lr < cnt) {
          float v1 = acc1[m][n][i], v3 = acc3[m][n][i];
          float hval = v1 / (1.f + expf(-v1)) * v3;
          h_buf[(size_t)(off + lr) * F_DIM + f0 + wc + n * 16 + fr] = (f16)hval;
        }
      }
}

// ================= down-proj =================
#define DN_STEP(RB)                                                              \
  do {                                                                           \
    { union { f16x8 v; f16x2 h[4]; } u;                                          \
      u.h[0] = pkrtz(RB[0], RB[1]); u.h[1] = pkrtz(RB[2], RB[3]);                \
      u.h[2] = pkrtz(RB[4], RB[5]); u.h[3] = pkrtz(RB[6], RB[7]);                \
      *(f16x8*)&B_lds[cur][bso] = u.v; }                                         \
    asm volatile("s_waitcnt lgkmcnt(0)" ::: "memory");                           \
    __builtin_amdgcn_s_barrier();                                                \
    { int kn = ((ti + 2) & 31) * 32;                                             \
      _Pragma("unroll") for (int j = 0; j < 8; ++j)                              \
        RB[j] = w2p[(size_t)(kn + j) * C_DIM];                                   \
      glds16(asrc[0] + kn, a_wr + wid * 512);                                    \
      glds16(asrc[1] + kn, a_wr + (8 + wid) * 512); }                            \
    asm volatile("s_waitcnt vmcnt(20)" ::: "memory");                            \
    { f16x8 a[4], b[4];                                                          \
      _Pragma("unroll") for (int m = 0; m < 4; ++m) {                            \
        int row = wr + m * 16 + fr;                                              \
        a[m] = *(const f16x8*)&a_rd0[row * 32 + (fq ^ ((row >> 1) & 3)) * 8]; }  \
      _Pragma("unroll") for (int n = 0; n < 4; ++n) {                            \
        int col = wc + n * 16 + fr;                                              \
        b[n] = *(const f16x8*)&B_lds[cur][col * 32 + (fq ^ ((col >> 1) & 3)) * 8]; } \
      _Pragma("unroll") for (int m = 0; m < 4; ++m)                              \
        _Pragma("unroll") for (int n = 0; n < 4; ++n)                            \
          acc[m][n] = __builtin_amdgcn_mfma_f32_16x16x32_f16(a[m], b[n], acc[m][n], 0, 0, 0); } \
    { f16* _t = a_rd0; a_rd0 = a_rd1; a_rd1 = a_wr; a_wr = _t; }                 \
    ++ti; cur ^= 1;                                                              \
  } while (0)

__launch_bounds__(512, 2)
__global__ void downproj_kernel(const f16* __restrict__ h_buf,
                                const float* __restrict__ w2,
                                const int* __restrict__ counts,
                                const int* __restrict__ offsets,
                                f16* __restrict__ y0,
                                f16* __restrict__ y1) {
  __shared__ f16 A_lds[3][BM * 32];
  __shared__ f16 B_lds[2][128 * 32];

  int bid = blockIdx.x;
  int e = bid & 7;
  int slot = bid >> 3;         // 0..127
  int kh = slot & 1;
  int tile = (slot >> 1) & 7;
  int cidx = slot >> 4;        // 0..7
  int cnt = counts[e];
  if (tile * BM >= cnt) return;
  f16* yb = kh ? y1 : y0;
  int row0 = tile * BM;
  int off = offsets[e];
  int c0 = cidx * 128;
  int t = threadIdx.x, wid = t >> 6, lane = t & 63;

  const f16* asrc[2];
#pragma unroll
  for (int p = 0; p < 2; ++p) {
    int c = (p * 8 + wid) * 64 + lane;
    int row = c >> 2, cc = c & 3;
    int lr = row0 + row; if (lr > cnt - 1) lr = cnt - 1;
    asrc[p] = h_buf + (size_t)(off + lr) * F_DIM + kh * 1024 + 8 * (cc ^ ((row >> 1) & 3));
  }

  int bcol = t & 127, kg = t >> 7;
  int bso = bcol * 32 + (kg ^ ((bcol >> 1) & 3)) * 8;
  const float* w2p = w2 + (size_t)e * F_DIM * C_DIM
                     + (size_t)(kh * 1024 + kg * 8) * C_DIM + c0 + bcol;

  f32x4 acc[4][4] = {};
  int wr = (wid >> 1) * 64, wc = (wid & 1) * 64;
  int fr = lane & 15, fq = lane >> 4;

  f16* a_rd0 = &A_lds[0][0];
  f16* a_rd1 = &A_lds[1][0];
  f16* a_wr  = &A_lds[2][0];

  float rA[8], rB[8];
#pragma unroll
  for (int j = 0; j < 8; ++j) rA[j] = w2p[(size_t)j * C_DIM];
  glds16(asrc[0], a_rd0 + wid * 512);
  glds16(asrc[1], a_rd0 + (8 + wid) * 512);
#pragma unroll
  for (int j = 0; j < 8; ++j) rB[j] = w2p[(size_t)(32 + j) * C_DIM];
  glds16(asrc[0] + 32, a_rd1 + wid * 512);
  glds16(asrc[1] + 32, a_rd1 + (8 + wid) * 512);

  int ti = 0, cur = 0;
  for (int tp = 0; tp < 16; ++tp) {
    DN_STEP(rA);
    DN_STEP(rB);
  }

#pragma unroll
  for (int m = 0; m < 4; ++m)
#pragma unroll
    for (int n = 0; n < 4; ++n)
#pragma unroll
      for (int i = 0; i < 4; ++i) {
        int lr = row0 + wr + m * 16 + fq * 4 + i;
        if (lr < cnt)
          yb[(size_t)(off + lr) * C_DIM + c0 + wc + n * 16 + fr] = (f16)acc[m][n][i];
      }
}

// ---------------- combine ----------------
__global__ void combine_kernel(const f16* __restrict__ y0, const f16* __restrict__ y1,
                               const int* __restrict__ slot_of,
                               const float* __restrict__ topw,
                               float* __restrict__ out) {
  int n = blockIdx.x;
  int s0 = slot_of[2 * n], s1 = slot_of[2 * n + 1];
  float g0 = topw[2 * n], g1 = topw[2 * n + 1];
  int c = threadIdx.x * 4;
  f16x4 a0 = *(const f16x4*)(y0 + (size_t)s0 * C_DIM + c);
  f16x4 a1 = *(const f16x4*)(y1 + (size_t)s0 * C_DIM + c);
  f16x4 b0 = *(const f16x4*)(y0 + (size_t)s1 * C_DIM + c);
  f16x4 b1 = *(const f16x4*)(y1 + (size_t)s1 * C_DIM + c);
  f32x4 o;
#pragma unroll
  for (int i = 0; i < 4; ++i)
    o[i] = g0 * ((float)a0[i] + (float)a1[i]) + g1 * ((float)b0[i] + (float)b1[i]);
  *(f32x4*)(out + (size_t)n * C_DIM + c) = o;
}

extern "C" void kernel_launch(void* const* d_in, const int* in_sizes, int n_in,
                              void* d_out, int out_size, void* d_ws, size_t ws_size,
                              hipStream_t stream) {
  const float* x  = (const float*)d_in[0];
  const float* Wr = (const float*)d_in[1];
  const float* w1 = (const float*)d_in[2];
  const float* w3 = (const float*)d_in[3];
  const float* w2 = (const float*)d_in[4];
  float* out = (float*)d_out;
  char* ws = (char*)d_ws;

  int* counts    = (int*)(ws + WS_COUNTS);
  int* offsets   = (int*)(ws + WS_OFFSETS);
  int* cursor    = (int*)(ws + WS_CURSOR);
  int* topi      = (int*)(ws + WS_TOPI);
  float* topw    = (float*)(ws + WS_TOPW);
  int* rows_perm = (int*)(ws + WS_ROWS);
  int* slot_of   = (int*)(ws + WS_SLOT);
  f16* x16       = (f16*)(ws + WS_X16);
  f16* h_buf     = (f16*)(ws + WS_H);
  f16* y0        = (f16*)(ws + WS_Y0);
  f16* y1        = (f16*)(ws + WS_Y1);

  (void)hipMemsetAsync(ws, 0, 256, stream);
  cvtx_kernel<<<N_TOK * C_DIM / 8 / 256, 256, 0, stream>>>(x, x16);
  router_kernel<<<N_TOK / 4, 256, 0, stream>>>(x, Wr, counts, topi, topw);
  scan_kernel<<<1, 64, 0, stream>>>(counts, offsets, cursor);
  scatter_kernel<<<N_TOK / 256, 256, 0, stream>>>(topi, cursor, rows_perm, slot_of);
  upproj_kernel<<<E_NUM * 128, 512, 0, stream>>>(
      x16, w1, w3, counts, offsets, rows_perm, h_buf);
  downproj_kernel<<<E_NUM * 128, 512, 0, stream>>>(
      h_buf, w2, counts, offsets, y0, y1);
  combine_kernel<<<N_TOK, 256, 0, stream>>>(y0, y1, slot_of, topw, out);
}